// Round 8
// baseline (248.831 us; speedup 1.0000x reference)
//
#include <hip/hip_runtime.h>
#include <hip/hip_bf16.h>

// Problem constants (from reference)
#define MA 60000
#define PA 20
#define CA 5
#define MR 80000
#define PR 32
#define CR 3
#define NXg 256
#define NYg 256
#define NB 8
#define NCELL (NB * NYg * NXg)   // 524288

typedef __bf16 bf16x8 __attribute__((ext_vector_type(8)));
typedef float  f32x4  __attribute__((ext_vector_type(4)));
typedef float  f4     __attribute__((ext_vector_type(4)));
typedef float  f2     __attribute__((ext_vector_type(2)));

__device__ __forceinline__ unsigned short f2bf(float f) {
    unsigned int u = __float_as_uint(f);
    u += 0x7fffu + ((u >> 16) & 1u);   // round-to-nearest-even
    return (unsigned short)(u >> 16);
}

// ---------------------------------------------------------------------------
// prep: winner-map = -1 via uint4 stores (4 MB, ~BW-bound couple of µs)
__global__ void __launch_bounds__(256) prep_kernel(uint4* __restrict__ win4) {
    uint4 m1 = {0xFFFFFFFFu, 0xFFFFFFFFu, 0xFFFFFFFFu, 0xFFFFFFFFu};
    win4[blockIdx.x * 256 + threadIdx.x] = m1;   // 1024*256 uint4 = 4 MB exact
}

// ---------------------------------------------------------------------------
// Pillar VFE v8 body: channel-major LDS staging + dup-fill, maskless pk math.
// G = 32 pillars/block (15.4 KB LDS -> up to 10 blocks/CU for latency hiding).
// Invalid slots [np, 8*ceil(np/8)) hold copies of point 0 -> max unchanged,
// sums corrected by (np8-np)*v0. pk pairs come straight from ds_read_b128.
template <int CIN, int CF, int PMAX, int PMAXp>
__device__ __forceinline__ void vfe_body(
    int bid, const float* __restrict__ vox, const int* __restrict__ coors,
    const int* __restrict__ npts, const float* __restrict__ W,
    const float* __restrict__ bias, unsigned short* __restrict__ feat,
    int* __restrict__ win, int M, int which, f4* sq)
{
    constexpr int G    = 32;               // pillars per block
    constexpr int PC   = PMAX * CIN;       // floats per pillar (source)
    constexpr int NF4v = PC / 4;           // 25 (agent) / 24 (rg)
    constexpr int SR   = PMAXp * CIN;      // floats per pillar (LDS region)
    constexpr int SR4  = SR / 4;
    constexpr int PP4  = PMAXp / 4;

    float* sf = (float*)sq;
    int tid  = threadIdx.x;
    int wv   = tid >> 6;
    int lane = tid & 63;
    int base = bid * G;
    int cnt  = M - base; cnt = cnt > G ? G : cnt;

    // ---- staging: coalesced global f4 -> channel-major LDS scatter ----
    {
        const f4* gv = (const f4*)vox + (size_t)base * NF4v;
        int totf4 = cnt * NF4v;
        for (int i = tid; i < totf4; i += 256) {
            f4 v = gv[i];
            int e = i * 4;                 // PC mult of 4 -> f4 never crosses
            int p = e / PC;
            int u = e - p * PC;
#pragma unroll
            for (int t = 0; t < 4; ++t) {
                int uu = u + t;
                int pt = uu / CIN;
                int c  = uu - pt * CIN;
                sf[p * SR + c * PMAXp + pt] = v[t];
            }
        }
    }

    // per-lane weight column + effective (folded) weights (overlaps staging)
    float wc[CF];
#pragma unroll
    for (int c = 0; c < CF; ++c) wc[c] = W[c * 64 + lane];
    float bd = bias[lane];
    f2 we2[CIN];
    we2[0] = (f2){wc[0] + wc[CIN + 0] + wc[CIN + 3], wc[0] + wc[CIN + 0] + wc[CIN + 3]};
    we2[1] = (f2){wc[1] + wc[CIN + 1] + wc[CIN + 4], wc[1] + wc[CIN + 1] + wc[CIN + 4]};
    we2[2] = (f2){wc[2] + wc[CIN + 2], wc[2] + wc[CIN + 2]};
#pragma unroll
    for (int c = 3; c < CIN; ++c) we2[c] = (f2){wc[c], wc[c]};

    __syncthreads();

    // ---- dup-fill: one lane per pillar copies point 0 into [np, np8) ----
    if (tid < cnt) {
        int np = npts[base + tid];
        np = np < 1 ? 1 : (np > PMAX ? PMAX : np);
        int np8 = (np + 7) & ~7;           // <= PMAXp
        float v0[CIN];
#pragma unroll
        for (int c = 0; c < CIN; ++c) v0[c] = sf[tid * SR + c * PMAXp];
        for (int p = np; p < np8; ++p)
#pragma unroll
            for (int c = 0; c < CIN; ++c)
                sf[tid * SR + c * PMAXp + p] = v0[c];
    }
    __syncthreads();

    // ---- meta prefetch (wave-uniform scalar loads) ----
    int np_n = 1, cb_n = 0, cy_n = 0, cx_n = 0;
    if (wv < cnt) {
        np_n = npts[base + wv];
        cb_n = coors[(base + wv) * 3 + 0];
        cy_n = coors[(base + wv) * 3 + 1];
        cx_n = coors[(base + wv) * 3 + 2];
    }

    // ---- compute: 8 pillars per wave, maskless pk math ----
    for (int pi = wv; pi < cnt; pi += 4) {
        int np = np_n, cb = cb_n, cy = cy_n, cx = cx_n;
        int pn = pi + 4;
        if (pn < cnt) {
            np_n = npts[base + pn];
            cb_n = coors[(base + pn) * 3 + 0];
            cy_n = coors[(base + pn) * 3 + 1];
            cx_n = coors[(base + pn) * 3 + 2];
        }
        np = np < 1 ? 1 : (np > PMAX ? PMAX : np);
        int nblk = (np + 7) >> 3;
        float kf = (float)(nblk * 8 - np);

        const f4* pf4 = sq + pi * SR4;
        const float* pf = sf + pi * SR;
        float x0 = pf[0], y0 = pf[PMAXp], z0 = pf[2 * PMAXp];

        f2 sx2 = {0.f, 0.f}, sy2 = {0.f, 0.f}, sz2 = {0.f, 0.f};
        f2 b2  = {-1e30f, -1e30f};

        for (int g = 0; g < nblk; ++g) {   // 8 points per block
            f4 lo[CIN], hi[CIN];
#pragma unroll
            for (int c = 0; c < CIN; ++c) {
                lo[c] = pf4[c * PP4 + g * 2];
                hi[c] = pf4[c * PP4 + g * 2 + 1];
            }
#pragma unroll
            for (int h = 0; h < 2; ++h) {  // lo half, hi half (4 points each)
#pragma unroll
                for (int j = 0; j < 2; ++j) {   // pair within half
                    f2 x2 = h ? (f2){hi[0][2*j], hi[0][2*j+1]} : (f2){lo[0][2*j], lo[0][2*j+1]};
                    f2 y2 = h ? (f2){hi[1][2*j], hi[1][2*j+1]} : (f2){lo[1][2*j], lo[1][2*j+1]};
                    f2 z2 = h ? (f2){hi[2][2*j], hi[2][2*j+1]} : (f2){lo[2][2*j], lo[2][2*j+1]};
                    sx2 += x2; sy2 += y2; sz2 += z2;
                    f2 d2 = x2 * we2[0] + y2 * we2[1] + z2 * we2[2];
#pragma unroll
                    for (int c = 3; c < CIN; ++c) {
                        f2 e2 = h ? (f2){hi[c][2*j], hi[c][2*j+1]} : (f2){lo[c][2*j], lo[c][2*j+1]};
                        d2 += e2 * we2[c];
                    }
                    b2 = __builtin_elementwise_max(b2, d2);
                }
            }
        }

        // dup-corrected sums; max unaffected by dups of point 0
        float sx = sx2[0] + sx2[1] - kf * x0;
        float sy = sy2[0] + sy2[1] - kf * y0;
        float sz = sz2[0] + sz2[1] - kf * z0;
        float sbest = fmaxf(b2[0], b2[1]);

        float inv = 1.0f / (float)np;
        float mx = sx * inv, my = sy * inv, mz = sz * inv;
        float xo = (float)cx * 0.3125f + (-39.84375f);   // VX, X_OFF exact
        float yo = (float)cy * 0.3125f + (-19.84375f);
        float off = bd - (mx * wc[CIN + 0] + my * wc[CIN + 1] + mz * wc[CIN + 2])
                       - xo * wc[CIN + 3] - yo * wc[CIN + 4];
        float best = fmaxf(0.0f, sbest + off);

        feat[(size_t)(base + pi) * 64 + lane] = f2bf(best);

        if (lane == 0) {
            // numpy last-write-wins == max pillar index wins; int2 map
            atomicMax(&win[((cb * NYg + cy) * NXg + cx) * 2 + which], base + pi);
        }
    }
}

// Unified VFE launch: blocks [0,1875) agent, [1875,4375) rg,
// [4375,4519) conv-weight B-fragment pack (stream-ordered before conv).
__global__ void __launch_bounds__(256) vfe_all(
    const float* __restrict__ vox_a, const int* __restrict__ coor_a,
    const int* __restrict__ np_a, const float* __restrict__ w_a,
    const float* __restrict__ b_a, unsigned short* __restrict__ feat_a,
    const float* __restrict__ vox_r, const int* __restrict__ coor_r,
    const int* __restrict__ np_r, const float* __restrict__ w_r,
    const float* __restrict__ b_r, unsigned short* __restrict__ feat_r,
    int* __restrict__ win, const float* __restrict__ conv_w,
    unsigned short* __restrict__ bp)
{
    __shared__ f4 sq[32 * 30];             // 15,360 B (agent: 32*120 floats)
    constexpr int NBA = (MA + 31) / 32;    // 1875
    constexpr int NBR = (MR + 31) / 32;    // 2500
    int bid = blockIdx.x;
    if (bid < NBA) {
        vfe_body<CA, CA + 5, PA, 24>(bid, vox_a, coor_a, np_a, w_a, b_a,
                                     feat_a, win, MA, 0, sq);
    } else if (bid < NBA + NBR) {
        vfe_body<CR, CR + 5, PR, 32>(bid - NBA, vox_r, coor_r, np_r, w_r, b_r,
                                     feat_r, win, MR, 1, sq);
    } else {
        // pack conv weights: offset = tap*4096 + kk*1024 + nt*512 + lane*8 + j
        //   n = nt*16+(lane&15), k = kk*32+(lane>>4)*8+j
        int i = (bid - NBA - NBR) * 256 + threadIdx.x;   // < 144*256 = 36864
        int j    = i & 7;
        int lane = (i >> 3) & 63;
        int nt   = (i >> 9) & 1;
        int kk   = (i >> 10) & 3;
        int tap  = i >> 12;
        int n = nt * 16 + (lane & 15);
        int k = kk * 32 + (lane >> 4) * 8 + j;
        bp[i] = f2bf(conv_w[(tap * 128 + k) * 32 + n]);
    }
}

// ---------------------------------------------------------------------------
// Conv v5: 4 channel-phases of 32 with REGISTER-PREFETCH pipeline.
// Block = 4 output rows x 64 cells; per phase stage 396 halo cells x 32 ch
// into LDS (cell stride 5 uint4 = 80 B, odd 16B-stride), 9 taps x 4 Mtiles
// x 2 Ntiles MFMA. Next phase's global loads are issued BEFORE the compute
// of the current phase, so HBM/L2 latency hides under 72 MFMAs.
__global__ void __launch_bounds__(256) conv_kernel(
    const unsigned short* __restrict__ feat_a,
    const unsigned short* __restrict__ feat_r,
    const int2* __restrict__ win2,            // {agent, rg} per cell
    const unsigned short* __restrict__ bpack,
    const float* __restrict__ conv_b,
    float* __restrict__ out)
{
    __shared__ uint4 sA[396 * 5];             // 31,680 B (5th uint4 = pad)

    int tid  = threadIdx.x;
    int lane = tid & 63;
    int wv   = tid >> 6;
    int bid  = blockIdx.x;
    int xg = bid & 3, yg = (bid >> 2) & 63, b = bid >> 8;
    int x0 = xg * 64, y0 = yg * 4;
    int mrow = lane & 15, quad = lane >> 4;

    // winner indices for this thread's (up to) 2 halo cells — loaded ONCE
    int wA[2] = {-1, -1}, wR[2] = {-1, -1};
#pragma unroll
    for (int r = 0; r < 2; ++r) {
        int cell = tid + r * 256;
        if (cell < 396) {
            int iy = cell / 66, ix = cell - iy * 66;
            int yy = y0 - 1 + iy, xx = x0 - 1 + ix;
            if ((unsigned)yy < 256u && (unsigned)xx < 256u) {
                int2 w2 = win2[(((b << 8) + yy) << 8) + xx];
                wA[r] = w2.x; wR[r] = w2.y;
            }
        }
    }

    f32x4 acc0[4], acc1[4];
#pragma unroll
    for (int mt = 0; mt < 4; ++mt) {
        acc0[mt] = (f32x4){0.f, 0.f, 0.f, 0.f};
        acc1[mt] = (f32x4){0.f, 0.f, 0.f, 0.f};
    }

    // prefetch phase 0 (agent, low 32 ch) into registers
    uint4 rbuf[2][4];
#pragma unroll
    for (int r = 0; r < 2; ++r) {
        int cell = tid + r * 256;
        if (cell < 396 && wA[r] >= 0) {
            const uint4* src = (const uint4*)(feat_a + ((long)wA[r] << 6));
#pragma unroll
            for (int s = 0; s < 4; ++s) rbuf[r][s] = src[s];
        }
    }

#pragma unroll
    for (int ph = 0; ph < 4; ++ph) {
        // ---- write staged registers (or zeros) to LDS ----
#pragma unroll
        for (int r = 0; r < 2; ++r) {
            int cell = tid + r * 256;
            if (cell < 396) {
                int w = (ph < 2) ? wA[r] : wR[r];
                uint4* dst = &sA[cell * 5];
                if (w >= 0) {
                    dst[0] = rbuf[r][0]; dst[1] = rbuf[r][1];
                    dst[2] = rbuf[r][2]; dst[3] = rbuf[r][3];
                } else {
                    uint4 zz = {0, 0, 0, 0};
                    dst[0] = zz; dst[1] = zz; dst[2] = zz; dst[3] = zz;
                }
            }
        }
        // ---- issue next phase's global loads (consumed next iteration) ----
        if (ph < 3) {
            const unsigned short* featn = (ph + 1 < 2) ? feat_a : feat_r;
            const int halfn = ((ph + 1) & 1) * 32;
#pragma unroll
            for (int r = 0; r < 2; ++r) {
                int cell = tid + r * 256;
                int w = (ph + 1 < 2) ? wA[r] : wR[r];
                if (cell < 396 && w >= 0) {
                    const uint4* src = (const uint4*)(featn + ((long)w << 6) + halfn);
#pragma unroll
                    for (int s = 0; s < 4; ++s) rbuf[r][s] = src[s];
                }
            }
        }
        __syncthreads();

        // ---- compute: kk = ph, 9 taps x 4 Mtiles x 2 Ntiles ----
#pragma unroll
        for (int tap = 0; tap < 9; ++tap) {
            const int dyo = tap / 3, dxo = tap % 3;
            const unsigned short* bp = bpack + tap * 4096 + ph * 1024 + lane * 8;
            bf16x8 bn0 = *(const bf16x8*)(bp);
            bf16x8 bn1 = *(const bf16x8*)(bp + 512);
            int iy = wv + dyo;
#pragma unroll
            for (int mt = 0; mt < 4; ++mt) {
                int ix = mt * 16 + mrow + dxo;
                bf16x8 a = *(const bf16x8*)(&sA[(iy * 66 + ix) * 5 + quad]);
                acc0[mt] = __builtin_amdgcn_mfma_f32_16x16x32_bf16(a, bn0, acc0[mt], 0, 0, 0);
                acc1[mt] = __builtin_amdgcn_mfma_f32_16x16x32_bf16(a, bn1, acc1[mt], 0, 0, 0);
            }
        }
        __syncthreads();
    }

    // ---- Epilogue: D layout col=lane&15, row=quad*4+reg ----
    int col = lane & 15;
    float bias0 = conv_b[col];
    float bias1 = conv_b[col + 16];
    int cellbase = ((((b << 8) + y0 + wv)) << 8) + x0;
#pragma unroll
    for (int mt = 0; mt < 4; ++mt) {
#pragma unroll
        for (int r = 0; r < 4; ++r) {
            int cell = cellbase + mt * 16 + quad * 4 + r;
            float* o = out + (long)cell * 32;
            o[col]      = acc0[mt][r] + bias0;
            o[col + 16] = acc1[mt][r] + bias1;
        }
    }
}

// ---------------------------------------------------------------------------
extern "C" void kernel_launch(void* const* d_in, const int* in_sizes, int n_in,
                              void* d_out, int out_size, void* d_ws, size_t ws_size,
                              hipStream_t stream)
{
    const float* vox_a  = (const float*)d_in[0];
    const int*   coor_a = (const int*)d_in[1];
    const int*   np_a   = (const int*)d_in[2];
    const float* vox_r  = (const float*)d_in[3];
    const int*   coor_r = (const int*)d_in[4];
    const int*   np_r   = (const int*)d_in[5];
    const float* w_a    = (const float*)d_in[6];
    const float* b_a    = (const float*)d_in[7];
    const float* w_r    = (const float*)d_in[8];
    const float* b_r    = (const float*)d_in[9];
    const float* conv_w = (const float*)d_in[10];
    const float* conv_b = (const float*)d_in[11];
    float* out = (float*)d_out;

    // Workspace layout (16B-aligned offsets), total ~22.2 MB
    char* ws = (char*)d_ws;
    unsigned short* feat_a = (unsigned short*)(ws);                          // 7,680,000 B
    unsigned short* feat_r = (unsigned short*)(ws + 7680000);                // 10,240,000 B
    int* win               = (int*)(ws + 17920000);                          // 4,194,304 B (int2/cell)
    unsigned short* bpack  = (unsigned short*)(ws + 17920000 + 4194304);     // 73,728 B

    // 1) winner map = -1 (uint4 stores, 4 MB)
    hipLaunchKernelGGL(prep_kernel, dim3(1024), dim3(256), 0, stream, (uint4*)win);
    // 2) unified VFE (agent + rg) + conv-weight pack tail
    constexpr int NBA = (MA + 31) / 32, NBR = (MR + 31) / 32;
    hipLaunchKernelGGL(vfe_all, dim3(NBA + NBR + 144), dim3(256), 0, stream,
                       vox_a, coor_a, np_a, w_a, b_a, feat_a,
                       vox_r, coor_r, np_r, w_r, b_r, feat_r, win, conv_w, bpack);
    // 3) conv v5: block = 4 rows x 64 cells, 4 channel-phases, reg-prefetch
    hipLaunchKernelGGL(conv_kernel, dim3(2048), dim3(256), 0, stream,
                       feat_a, feat_r, (const int2*)win, bpack, conv_b, out);
}